// Round 4
// baseline (145.808 us; speedup 1.0000x reference)
//
#include <hip/hip_runtime.h>

// Chamfer distance: B=8, N=M=8192, D=3, fp32.
// R4: (a) dst operand is block-uniform -> read via SCALAR loads (s_load) from a
//         pre-packed global float4 array (-2x,-2y,-2z,|g|^2); no LDS, no
//         syncthreads, no ds_read in the vector issue stream.
//     (b) src points held as 4x float2, math via __builtin_elementwise_fma/min
//         -> v_pk_fma_f32 / v_pk_min_f32: 2 pk instr per pair instead of 4.
// Scalar floor 55us; if pk-fp32 is double-rate (gfx90a lineage), 27us.

#define B_DIM 8
#define N_DIM 8192
#define SPLIT 16
#define PPT   8                      // as 4 x float2
#define BLOCK 256
#define JRANGE (N_DIM / SPLIT)       // 512

typedef float v2f __attribute__((ext_vector_type(2)));

__device__ __forceinline__ unsigned int f32_to_ordered_u32(float f) {
    unsigned int u = __float_as_uint(f);
    return (u & 0x80000000u) ? ~u : (u | 0x80000000u);
}
__device__ __forceinline__ float ordered_u32_to_f32(unsigned int k) {
    return __uint_as_float((k & 0x80000000u) ? (k & 0x7fffffffu) : ~k);
}

// Pack dst points for both directions and init the atomic-min keys.
__global__ __launch_bounds__(256) void chamfer_prep(
    const float* __restrict__ pred, const float* __restrict__ gt,
    float4* __restrict__ packed, unsigned int* __restrict__ keys)
{
    const int i   = blockIdx.x * 256 + threadIdx.x;  // 0 .. 2*B*N-1
    const int dir = i >> 16;                         // 0: dst=gt, 1: dst=pred
    const int bm  = i & 0xFFFF;                      // b*8192 + m
    const float* dst = dir ? pred : gt;
    const float gx = dst[3*bm+0], gy = dst[3*bm+1], gz = dst[3*bm+2];
    packed[i] = make_float4(-2.0f*gx, -2.0f*gy, -2.0f*gz,
                            gx*gx + gy*gy + gz*gz);
    keys[i] = 0xFFFFFFFFu;
}

__global__ __launch_bounds__(BLOCK, 4) void chamfer_partial(
    const float* __restrict__ pred, const float* __restrict__ gt,
    const float4* __restrict__ packed, unsigned int* __restrict__ keys)
{
    const int tid   = threadIdx.x;
    const int z     = blockIdx.z;        // b + dir*8
    const int b     = z & (B_DIM - 1);
    const int dir   = z >> 3;
    const int s     = blockIdx.y;
    const int chunk = blockIdx.x;        // 0..3

    const float* src  = dir ? gt : pred;
    const float* srcb = src + (size_t)b * N_DIM * 3;
    const float4* pk  = packed + ((size_t)dir * B_DIM + b) * N_DIM + s * JRANGE;

    // 8 src points per thread, packed as 4 float2 (pairs stride BLOCK apart)
    v2f px[4], py[4], pz[4], best[4];
    const int nbase = chunk * (BLOCK * PPT) + tid;
    #pragma unroll
    for (int q = 0; q < 4; ++q) {
        const int n0 = nbase + (2*q  ) * BLOCK;
        const int n1 = nbase + (2*q+1) * BLOCK;
        px[q] = (v2f){srcb[n0*3+0], srcb[n1*3+0]};
        py[q] = (v2f){srcb[n0*3+1], srcb[n1*3+1]};
        pz[q] = (v2f){srcb[n0*3+2], srcb[n1*3+2]};
        best[q] = (v2f){1e30f, 1e30f};
    }

    #pragma unroll 4
    for (int j = 0; j < JRANGE; ++j) {
        const float4 g = pk[j];          // uniform index -> s_load
        const v2f gx = (v2f){g.x, g.x};
        const v2f gy = (v2f){g.y, g.y};
        const v2f gz = (v2f){g.z, g.z};
        const v2f gw = (v2f){g.w, g.w};
        #pragma unroll
        for (int q = 0; q < 4; ++q) {
            v2f d = __builtin_elementwise_fma(pz[q], gz, gw);
            d     = __builtin_elementwise_fma(py[q], gy, d);
            d     = __builtin_elementwise_fma(px[q], gx, d);
            best[q] = __builtin_elementwise_min(best[q], d);
        }
    }

    unsigned int* kb = keys + ((size_t)dir * B_DIM + b) * N_DIM;
    #pragma unroll
    for (int q = 0; q < 4; ++q) {
        const v2f pn = __builtin_elementwise_fma(px[q], px[q],
                       __builtin_elementwise_fma(py[q], py[q],
                       pz[q] * pz[q]));
        const v2f v = best[q] + pn;
        atomicMin(&kb[nbase + (2*q  ) * BLOCK], f32_to_ordered_u32(v.x));
        atomicMin(&kb[nbase + (2*q+1) * BLOCK], f32_to_ordered_u32(v.y));
    }
}

__global__ __launch_bounds__(256) void chamfer_reduce(
    const unsigned int* __restrict__ keys, float* __restrict__ out)
{
    const float scale = 100.0f * 0.5f / ((float)B_DIM * (float)N_DIM);
    const int i = (blockIdx.x * 256 + threadIdx.x) * 4;
    const uint4 k = *(const uint4*)(keys + i);
    float v = ordered_u32_to_f32(k.x) + ordered_u32_to_f32(k.y)
            + ordered_u32_to_f32(k.z) + ordered_u32_to_f32(k.w);
    for (int off = 32; off > 0; off >>= 1)
        v += __shfl_down(v, off, 64);
    __shared__ float wsum[4];
    const int lane = threadIdx.x & 63, w = threadIdx.x >> 6;
    if (lane == 0) wsum[w] = v;
    __syncthreads();
    if (threadIdx.x == 0) {
        const float t = wsum[0] + wsum[1] + wsum[2] + wsum[3];
        atomicAdd(out, t * scale);
    }
}

extern "C" void kernel_launch(void* const* d_in, const int* in_sizes, int n_in,
                              void* d_out, int out_size, void* d_ws, size_t ws_size,
                              hipStream_t stream) {
    const float* pred = (const float*)d_in[0];
    const float* gt   = (const float*)d_in[1];
    float* out = (float*)d_out;
    // ws: [0, 512KB) ordered-u32 min keys; [512KB, 2.5MB) packed dst float4
    unsigned int* keys = (unsigned int*)d_ws;
    float4* packed = (float4*)((char*)d_ws + (size_t)2 * B_DIM * N_DIM * 4);

    hipMemsetAsync(out, 0, sizeof(float), stream);

    chamfer_prep<<<(2 * B_DIM * N_DIM) / 256, 256, 0, stream>>>(pred, gt, packed, keys);

    dim3 grid(N_DIM / (BLOCK * PPT), SPLIT, 2 * B_DIM);  // 4 x 16 x 16 = 1024
    chamfer_partial<<<grid, BLOCK, 0, stream>>>(pred, gt, packed, keys);

    chamfer_reduce<<<(2 * B_DIM * N_DIM) / (256 * 4), 256, 0, stream>>>(keys, out);
}

// Round 5
// 116.444 us; speedup vs baseline: 1.2522x; 1.2522x over previous
//
#include <hip/hip_runtime.h>

// Chamfer distance: B=8, N=M=8192, D=3, fp32, via bf16 split-precision MFMA.
// d(n,m) = |p|^2 + |g|^2 - 2 p.g  computed as ONE v_mfma_f32_32x32x16_bf16 per
// 32x32 tile: K slots = [ah*gh(3) | ah*gl(3) | al*gh(3) | pn_h,pn_l x 1 |
// 1 x gn_h,gn_l | 0,0,0] with a = -2p split hi/lo bf16. Dropped al*gl term
// ~1e-4 abs (threshold 4.7e-2). Per tile: 1 MFMA (~8cyc, MFMA pipe) + 16 v_min
// (32cyc VALU). VALU floor 13.7us vs 55us for any fp32-VALU formulation.
// B-fragments pre-packed in exact lane order; one dword x4 load/lane/tile.

#define B_DIM 8
#define N_DIM 8192
#define MT    (N_DIM / 32)      // 256 m-tiles per (dir,b)
#define BLOCK 256

typedef short  bf16x8 __attribute__((ext_vector_type(8)));
typedef float  f32x16 __attribute__((ext_vector_type(16)));

__device__ __forceinline__ unsigned short bf16_rne(float f) {
    unsigned int u = __float_as_uint(f);
    u += 0x7fffu + ((u >> 16) & 1u);
    return (unsigned short)(u >> 16);
}
__device__ __forceinline__ float bf16f(unsigned short h) {
    return __uint_as_float(((unsigned int)h) << 16);
}

// Pack B-fragments for both directions. Layout: 16-byte frags indexed
// [dirb][mtile][half][n32] so a wave's 64 lanes read 1024 contiguous bytes.
__global__ __launch_bounds__(256) void chamfer_prep(
    const float* __restrict__ pred, const float* __restrict__ gt,
    unsigned short* __restrict__ bpack)
{
    const int i   = blockIdx.x * 256 + threadIdx.x;  // 0 .. 2*B*N-1
    const int dir = i >> 16;
    const int bm  = i & 0xFFFF;                      // b*N + m
    const float* dst = dir ? pred : gt;
    const float x = dst[3*bm+0], y = dst[3*bm+1], z = dst[3*bm+2];
    const unsigned short hx = bf16_rne(x), hy = bf16_rne(y), hz = bf16_rne(z);
    const unsigned short lx = bf16_rne(x - bf16f(hx));
    const unsigned short ly = bf16_rne(y - bf16f(hy));
    const unsigned short lz = bf16_rne(z - bf16f(hz));
    const float gn = x*x + y*y + z*z;
    const unsigned short gnh = bf16_rne(gn), gnl = bf16_rne(gn - bf16f(gnh));
    const unsigned short one = 0x3F80;

    const int b  = bm >> 13, m = bm & (N_DIM - 1);
    const int mt = m >> 5,   n = m & 31;
    const int dirb = (dir << 3) | b;
    unsigned short* p0 = bpack + ((size_t)(dirb * MT + mt) * 64 + n) * 8;
    unsigned short* p1 = p0 + 32 * 8;
    // half0 = k0..7 : gh(xyz) gl(xyz) gh(x,y) ; half1 = k8..15 : gh(z) 1 1 gnh gnl 0 0 0
    bf16x8 h0 = {(short)hx,(short)hy,(short)hz,(short)lx,(short)ly,(short)lz,(short)hx,(short)hy};
    bf16x8 h1 = {(short)hz,(short)one,(short)one,(short)gnh,(short)gnl,0,0,0};
    *(bf16x8*)p0 = h0;
    *(bf16x8*)p1 = h1;
}

__global__ __launch_bounds__(BLOCK, 4) void chamfer_partial(
    const float* __restrict__ pred, const float* __restrict__ gt,
    const bf16x8* __restrict__ bpack, float* __restrict__ minv)
{
    const int dirb = blockIdx.x;            // low grid bits -> XCD locality
    const int dir  = dirb >> 3, b = dirb & 7;
    const int wave = threadIdx.x >> 6, lane = threadIdx.x & 63;
    const int half = lane >> 5,  col = lane & 31;
    const int ntile = blockIdx.y * 4 + wave;

    const float* src  = dir ? gt : pred;
    const float* srcb = src + (size_t)b * N_DIM * 3;

    // Build A fragment for this wave's 32 src rows (row = col, k-half = half).
    const int n = ntile * 32 + col;
    const float x = srcb[3*n+0], y = srcb[3*n+1], z = srcb[3*n+2];
    const float ax = -2.f*x, ay = -2.f*y, az = -2.f*z;
    const unsigned short ahx = bf16_rne(ax), ahy = bf16_rne(ay), ahz = bf16_rne(az);
    const unsigned short alx = bf16_rne(ax - bf16f(ahx));
    const unsigned short aly = bf16_rne(ay - bf16f(ahy));
    const unsigned short alz = bf16_rne(az - bf16f(ahz));
    const float pn = x*x + y*y + z*z;
    const unsigned short pnh = bf16_rne(pn), pnl = bf16_rne(pn - bf16f(pnh));
    const unsigned short one = 0x3F80;
    bf16x8 a0 = {(short)ahx,(short)ahy,(short)ahz,(short)ahx,(short)ahy,(short)ahz,(short)alx,(short)aly};
    bf16x8 a1 = {(short)alz,(short)pnh,(short)pnl,(short)one,(short)one,0,0,0};
    bf16x8 afrag;
    if (half == 0) afrag = a0; else afrag = a1;

    const bf16x8* bp = bpack + (size_t)dirb * MT * 64;
    const f32x16 czero = {0.f,0.f,0.f,0.f,0.f,0.f,0.f,0.f,
                          0.f,0.f,0.f,0.f,0.f,0.f,0.f,0.f};
    float best[16];
    #pragma unroll
    for (int r = 0; r < 16; ++r) best[r] = 1e30f;

    bf16x8 bcur = bp[lane];
    #pragma unroll 2
    for (int t = 0; t < MT; ++t) {
        if ((t & 15) == 0) __syncthreads();   // keep 4 waves L1-convergent
        const int tn = (t + 1 < MT) ? t + 1 : MT - 1;
        const bf16x8 bc = bcur;
        bcur = bp[tn * 64 + lane];            // prefetch next tile's fragment
        f32x16 d = __builtin_amdgcn_mfma_f32_32x32x16_bf16(afrag, bc, czero, 0, 0, 0);
        #pragma unroll
        for (int r = 0; r < 16; ++r) best[r] = fminf(best[r], d[r]);
    }

    // Min across the 32 lanes of this half (same 16 rows, 32 m-residues).
    #pragma unroll
    for (int r = 0; r < 16; ++r) {
        float v = best[r];
        v = fminf(v, __shfl_xor(v, 1,  64));
        v = fminf(v, __shfl_xor(v, 2,  64));
        v = fminf(v, __shfl_xor(v, 4,  64));
        v = fminf(v, __shfl_xor(v, 8,  64));
        v = fminf(v, __shfl_xor(v, 16, 64));
        best[r] = v;
    }
    // C/D row = (reg&3) + 8*(reg>>2) + 4*half ; one owner wave per n -> plain store
    float* mb = minv + (size_t)dirb * N_DIM + ntile * 32;
    #pragma unroll
    for (int r = 0; r < 16; ++r) {
        const int row = (r & 3) + 8 * (r >> 2) + 4 * half;
        if (col == r) mb[row] = best[r];
    }
}

__global__ __launch_bounds__(1024) void chamfer_reduce(
    const float* __restrict__ minv, float* __restrict__ out)
{
    const float scale = 100.0f * 0.5f / ((float)B_DIM * (float)N_DIM);
    float s = 0.f;
    const float4* v4 = (const float4*)minv;
    for (int i = threadIdx.x; i < (2 * B_DIM * N_DIM) / 4; i += 1024) {
        const float4 v = v4[i];
        s += (v.x + v.y) + (v.z + v.w);
    }
    for (int off = 32; off > 0; off >>= 1) s += __shfl_down(s, off, 64);
    __shared__ float wsum[16];
    if ((threadIdx.x & 63) == 0) wsum[threadIdx.x >> 6] = s;
    __syncthreads();
    if (threadIdx.x == 0) {
        float t = 0.f;
        #pragma unroll
        for (int k = 0; k < 16; ++k) t += wsum[k];
        out[0] = t * scale;   // full overwrite: no memset node needed
    }
}

extern "C" void kernel_launch(void* const* d_in, const int* in_sizes, int n_in,
                              void* d_out, int out_size, void* d_ws, size_t ws_size,
                              hipStream_t stream) {
    const float* pred = (const float*)d_in[0];
    const float* gt   = (const float*)d_in[1];
    float* out = (float*)d_out;
    // ws: [0, 4MiB) packed B-fragments ; [4MiB, 4.5MiB) per-point minima
    unsigned short* bpack = (unsigned short*)d_ws;
    float* minv = (float*)((char*)d_ws + (size_t)16 * MT * 64 * 16);

    chamfer_prep<<<(2 * B_DIM * N_DIM) / 256, 256, 0, stream>>>(pred, gt, bpack);

    dim3 grid(16, N_DIM / (32 * 4));   // dirb x n-chunks = 16 x 64 = 1024 blocks
    chamfer_partial<<<grid, BLOCK, 0, stream>>>(pred, gt, (const bf16x8*)bpack, minv);

    chamfer_reduce<<<1, 1024, 0, stream>>>(minv, out);
}

// Round 6
// 99.178 us; speedup vs baseline: 1.4702x; 1.1741x over previous
//
#include <hip/hip_runtime.h>

// Chamfer distance: B=8, N=M=8192, D=3, fp32, via bf16 split-precision MFMA.
// R6: R5 was L2-latency/BW bound (every wave re-read 256KB of B-fragments from
// L2; 18.7 TB/s agg, 1 outstanding load/wave, VALUBusy 35%). Fix: m97-style
// double-buffered LDS staging -- block's 4 waves share one load of the stream
// (4x L2 traffic cut), inner loop reads ds_read_b128 (short latency).
// Per tile: 1 ds_read + 1 MFMA (32x32 tile = 1024 pairs) + 16 v_min.
// VALU floor ~17us; predict partial ~22-27us.

#define B_DIM 8
#define N_DIM 8192
#define MT    (N_DIM / 32)      // 256 m-tiles per (dir,b)
#define CH    16                // tiles per staged chunk (16 KB)
#define NC    (MT / CH)         // 16 chunks
#define BLOCK 256

typedef short  bf16x8 __attribute__((ext_vector_type(8)));
typedef float  f32x16 __attribute__((ext_vector_type(16)));

__device__ __forceinline__ unsigned short bf16_rne(float f) {
    unsigned int u = __float_as_uint(f);
    u += 0x7fffu + ((u >> 16) & 1u);
    return (unsigned short)(u >> 16);
}
__device__ __forceinline__ float bf16f(unsigned short h) {
    return __uint_as_float(((unsigned int)h) << 16);
}

// Pack B-fragments for both directions. Layout: 16-byte frags indexed
// [dirb][mtile][half][n32] so a wave's 64 lanes read 1024 contiguous bytes.
__global__ __launch_bounds__(256) void chamfer_prep(
    const float* __restrict__ pred, const float* __restrict__ gt,
    unsigned short* __restrict__ bpack)
{
    const int i   = blockIdx.x * 256 + threadIdx.x;  // 0 .. 2*B*N-1
    const int dir = i >> 16;
    const int bm  = i & 0xFFFF;                      // b*N + m
    const float* dst = dir ? pred : gt;
    const float x = dst[3*bm+0], y = dst[3*bm+1], z = dst[3*bm+2];
    const unsigned short hx = bf16_rne(x), hy = bf16_rne(y), hz = bf16_rne(z);
    const unsigned short lx = bf16_rne(x - bf16f(hx));
    const unsigned short ly = bf16_rne(y - bf16f(hy));
    const unsigned short lz = bf16_rne(z - bf16f(hz));
    const float gn = x*x + y*y + z*z;
    const unsigned short gnh = bf16_rne(gn), gnl = bf16_rne(gn - bf16f(gnh));
    const unsigned short one = 0x3F80;

    const int b  = bm >> 13, m = bm & (N_DIM - 1);
    const int mt = m >> 5,   n = m & 31;
    const int dirb = (dir << 3) | b;
    unsigned short* p0 = bpack + ((size_t)(dirb * MT + mt) * 64 + n) * 8;
    unsigned short* p1 = p0 + 32 * 8;
    // half0 = k0..7 : gh(xyz) gl(xyz) gh(x,y) ; half1 = k8..15 : gh(z) 1 1 gnh gnl 0 0 0
    bf16x8 h0 = {(short)hx,(short)hy,(short)hz,(short)lx,(short)ly,(short)lz,(short)hx,(short)hy};
    bf16x8 h1 = {(short)hz,(short)one,(short)one,(short)gnh,(short)gnl,0,0,0};
    *(bf16x8*)p0 = h0;
    *(bf16x8*)p1 = h1;
}

__global__ __launch_bounds__(BLOCK, 4) void chamfer_partial(
    const float* __restrict__ pred, const float* __restrict__ gt,
    const bf16x8* __restrict__ bpack, float* __restrict__ minv)
{
    __shared__ bf16x8 sbuf[2][CH * 64];     // 2 x 16 KB double buffer
    const int dirb = blockIdx.x;            // low grid bits -> XCD locality
    const int dir  = dirb >> 3, b = dirb & 7;
    const int w    = threadIdx.x >> 6, lane = threadIdx.x & 63;
    const int half = lane >> 5,  col = lane & 31;
    const int ntile = blockIdx.y * 4 + w;

    const float* src  = dir ? gt : pred;
    const float* srcb = src + (size_t)b * N_DIM * 3;

    // A fragment for this wave's 32 src rows (row = col, k-half = half).
    const int n = ntile * 32 + col;
    const float x = srcb[3*n+0], y = srcb[3*n+1], z = srcb[3*n+2];
    const float ax = -2.f*x, ay = -2.f*y, az = -2.f*z;
    const unsigned short ahx = bf16_rne(ax), ahy = bf16_rne(ay), ahz = bf16_rne(az);
    const unsigned short alx = bf16_rne(ax - bf16f(ahx));
    const unsigned short aly = bf16_rne(ay - bf16f(ahy));
    const unsigned short alz = bf16_rne(az - bf16f(ahz));
    const float pn = x*x + y*y + z*z;
    const unsigned short pnh = bf16_rne(pn), pnl = bf16_rne(pn - bf16f(pnh));
    const unsigned short one = 0x3F80;
    bf16x8 a0 = {(short)ahx,(short)ahy,(short)ahz,(short)ahx,(short)ahy,(short)ahz,(short)alx,(short)aly};
    bf16x8 a1 = {(short)alz,(short)pnh,(short)pnl,(short)one,(short)one,0,0,0};
    const bf16x8 afrag = (half == 0) ? a0 : a1;

    const bf16x8* bp = bpack + (size_t)dirb * MT * 64;
    const f32x16 czero = {0.f,0.f,0.f,0.f,0.f,0.f,0.f,0.f,
                          0.f,0.f,0.f,0.f,0.f,0.f,0.f,0.f};
    float best[16];
    #pragma unroll
    for (int r = 0; r < 16; ++r) best[r] = 1e30f;

    // staging: each thread ferries 4 frags/chunk (64 B) via registers
    bf16x8 rg[4];
    const int soff = w * 256 + lane;        // this thread's frag slots
    #define GLOAD(c) { const bf16x8* g = bp + (size_t)(c) * (CH*64) + soff; \
        _Pragma("unroll") for (int i = 0; i < 4; ++i) rg[i] = g[i * 64]; }
    #define SWRITE(pb) { bf16x8* s = &sbuf[pb][soff]; \
        _Pragma("unroll") for (int i = 0; i < 4; ++i) s[i * 64] = rg[i]; }

    GLOAD(0); SWRITE(0); GLOAD(1);
    __syncthreads();

    for (int c = 0; c < NC; ++c) {
        const int pb = c & 1;
        if (c + 1 < NC) SWRITE(pb ^ 1);     // chunk c+1 -> other buffer
        if (c + 2 < NC) GLOAD(c + 2);       // refill regs, loads in flight
        #pragma unroll
        for (int j = 0; j < CH; ++j) {
            const bf16x8 bc = sbuf[pb][j * 64 + lane];
            f32x16 d = __builtin_amdgcn_mfma_f32_32x32x16_bf16(afrag, bc, czero, 0, 0, 0);
            #pragma unroll
            for (int r = 0; r < 16; ++r) best[r] = fminf(best[r], d[r]);
        }
        __syncthreads();
    }

    // Min across the 32 lanes of this half (same 16 rows, 32 m-residues).
    #pragma unroll
    for (int r = 0; r < 16; ++r) {
        float v = best[r];
        v = fminf(v, __shfl_xor(v, 1,  64));
        v = fminf(v, __shfl_xor(v, 2,  64));
        v = fminf(v, __shfl_xor(v, 4,  64));
        v = fminf(v, __shfl_xor(v, 8,  64));
        v = fminf(v, __shfl_xor(v, 16, 64));
        best[r] = v;
    }
    // C/D row = (reg&3) + 8*(reg>>2) + 4*half ; one owner wave per n -> plain store
    float* mb = minv + (size_t)dirb * N_DIM + ntile * 32;
    #pragma unroll
    for (int r = 0; r < 16; ++r) {
        const int row = (r & 3) + 8 * (r >> 2) + 4 * half;
        if (col == r) mb[row] = best[r];
    }
}

__global__ __launch_bounds__(256) void chamfer_reduce(
    const float* __restrict__ minv, float* __restrict__ out)
{
    const float scale = 100.0f * 0.5f / ((float)B_DIM * (float)N_DIM);
    const int i = blockIdx.x * 256 + threadIdx.x;    // 32768 float4s
    const float4 v = ((const float4*)minv)[i];
    float s = (v.x + v.y) + (v.z + v.w);
    for (int off = 32; off > 0; off >>= 1) s += __shfl_down(s, off, 64);
    __shared__ float wsum[4];
    if ((threadIdx.x & 63) == 0) wsum[threadIdx.x >> 6] = s;
    __syncthreads();
    if (threadIdx.x == 0)
        atomicAdd(out, (wsum[0] + wsum[1] + wsum[2] + wsum[3]) * scale);
}

extern "C" void kernel_launch(void* const* d_in, const int* in_sizes, int n_in,
                              void* d_out, int out_size, void* d_ws, size_t ws_size,
                              hipStream_t stream) {
    const float* pred = (const float*)d_in[0];
    const float* gt   = (const float*)d_in[1];
    float* out = (float*)d_out;
    // ws: [0, 4MiB) packed B-fragments ; [4MiB, 4.5MiB) per-point minima
    unsigned short* bpack = (unsigned short*)d_ws;
    float* minv = (float*)((char*)d_ws + (size_t)16 * MT * 64 * 16);

    hipMemsetAsync(out, 0, sizeof(float), stream);

    chamfer_prep<<<(2 * B_DIM * N_DIM) / 256, 256, 0, stream>>>(pred, gt, bpack);

    dim3 grid(16, N_DIM / (32 * 4));   // dirb x n-chunks = 16 x 64 = 1024 blocks
    chamfer_partial<<<grid, BLOCK, 0, stream>>>(pred, gt, (const bf16x8*)bpack, minv);

    chamfer_reduce<<<(2 * B_DIM * N_DIM) / (256 * 4), 256, 0, stream>>>(minv, out);
}

// Round 7
// 94.266 us; speedup vs baseline: 1.5468x; 1.0521x over previous
//
#include <hip/hip_runtime.h>

// Chamfer distance: B=8, N=M=8192, D=3, fp32, via bf16 split-precision MFMA.
// R7: (a) PPW=2: each wave computes 2 n-tiles per staged B-fragment ->
//         LDS bytes/pair halved (R6 was LDS-pipe-heaviest: ~20us/CU of
//         ds_read_b128 vs 14us VALU). Now ~10us LDS / ~8us VALU / 3.4us MFMA.
//     (b) 2 graph nodes: no m-split -> wave's row-mins are final -> in-kernel
//         sum + one atomicAdd(out)/block. Reduce + memset nodes deleted
//         (prep zeroes out[0]). R6 had ~56us of non-partial overhead.

#define B_DIM 8
#define N_DIM 8192
#define MT    (N_DIM / 32)      // 256 m-tiles per (dir,b)
#define CH    16                // tiles per staged chunk (16 KB)
#define NC    (MT / CH)         // 16 chunks
#define BLOCK 256
#define PPW   2                 // n-tiles per wave

typedef short  bf16x8 __attribute__((ext_vector_type(8)));
typedef float  f32x16 __attribute__((ext_vector_type(16)));

__device__ __forceinline__ unsigned short bf16_rne(float f) {
    unsigned int u = __float_as_uint(f);
    u += 0x7fffu + ((u >> 16) & 1u);
    return (unsigned short)(u >> 16);
}
__device__ __forceinline__ float bf16f(unsigned short h) {
    return __uint_as_float(((unsigned int)h) << 16);
}

// Pack B-fragments for both directions. Layout: 16-byte frags indexed
// [dirb][mtile][half][m32] so a wave's 64 lanes read 1024 contiguous bytes.
__global__ __launch_bounds__(256) void chamfer_prep(
    const float* __restrict__ pred, const float* __restrict__ gt,
    unsigned short* __restrict__ bpack, float* __restrict__ out)
{
    const int i   = blockIdx.x * 256 + threadIdx.x;  // 0 .. 2*B*N-1
    if (i == 0) out[0] = 0.0f;
    const int dir = i >> 16;
    const int bm  = i & 0xFFFF;                      // b*N + m
    const float* dst = dir ? pred : gt;
    const float x = dst[3*bm+0], y = dst[3*bm+1], z = dst[3*bm+2];
    const unsigned short hx = bf16_rne(x), hy = bf16_rne(y), hz = bf16_rne(z);
    const unsigned short lx = bf16_rne(x - bf16f(hx));
    const unsigned short ly = bf16_rne(y - bf16f(hy));
    const unsigned short lz = bf16_rne(z - bf16f(hz));
    const float gn = x*x + y*y + z*z;
    const unsigned short gnh = bf16_rne(gn), gnl = bf16_rne(gn - bf16f(gnh));
    const unsigned short one = 0x3F80;

    const int b  = bm >> 13, m = bm & (N_DIM - 1);
    const int mt = m >> 5,   c = m & 31;
    const int dirb = (dir << 3) | b;
    unsigned short* p0 = bpack + ((size_t)(dirb * MT + mt) * 64 + c) * 8;
    unsigned short* p1 = p0 + 32 * 8;
    // half0 = k0..7 : gh(xyz) gl(xyz) gh(x,y) ; half1 = k8..15 : gh(z) 1 1 gnh gnl 0 0 0
    bf16x8 h0 = {(short)hx,(short)hy,(short)hz,(short)lx,(short)ly,(short)lz,(short)hx,(short)hy};
    bf16x8 h1 = {(short)hz,(short)one,(short)one,(short)gnh,(short)gnl,0,0,0};
    *(bf16x8*)p0 = h0;
    *(bf16x8*)p1 = h1;
}

__global__ __launch_bounds__(BLOCK, 2) void chamfer_partial(
    const float* __restrict__ pred, const float* __restrict__ gt,
    const bf16x8* __restrict__ bpack, float* __restrict__ out)
{
    __shared__ bf16x8 sbuf[2][CH * 64];     // 2 x 16 KB double buffer
    __shared__ float wsum[4];
    const int dirb = blockIdx.x;            // low grid bits -> 2 streams/XCD in L2
    const int dir  = dirb >> 3, b = dirb & 7;
    const int w    = threadIdx.x >> 6, lane = threadIdx.x & 63;
    const int half = lane >> 5,  col = lane & 31;

    const float* src  = dir ? gt : pred;
    const float* srcb = src + (size_t)b * N_DIM * 3;

    // A fragments for this wave's PPW n-tiles (row = col, k-half = half).
    bf16x8 afrag[PPW];
    #pragma unroll
    for (int p = 0; p < PPW; ++p) {
        const int ntile = (blockIdx.y * 4 + w) * PPW + p;
        const int n = ntile * 32 + col;
        const float x = srcb[3*n+0], y = srcb[3*n+1], z = srcb[3*n+2];
        const float ax = -2.f*x, ay = -2.f*y, az = -2.f*z;
        const unsigned short ahx = bf16_rne(ax), ahy = bf16_rne(ay), ahz = bf16_rne(az);
        const unsigned short alx = bf16_rne(ax - bf16f(ahx));
        const unsigned short aly = bf16_rne(ay - bf16f(ahy));
        const unsigned short alz = bf16_rne(az - bf16f(ahz));
        const float pn = x*x + y*y + z*z;
        const unsigned short pnh = bf16_rne(pn), pnl = bf16_rne(pn - bf16f(pnh));
        const unsigned short one = 0x3F80;
        bf16x8 a0 = {(short)ahx,(short)ahy,(short)ahz,(short)ahx,(short)ahy,(short)ahz,(short)alx,(short)aly};
        bf16x8 a1 = {(short)alz,(short)pnh,(short)pnl,(short)one,(short)one,0,0,0};
        afrag[p] = (half == 0) ? a0 : a1;
    }

    const bf16x8* bp = bpack + (size_t)dirb * MT * 64;
    const f32x16 czero = {0.f,0.f,0.f,0.f,0.f,0.f,0.f,0.f,
                          0.f,0.f,0.f,0.f,0.f,0.f,0.f,0.f};
    float best[PPW][16];
    #pragma unroll
    for (int p = 0; p < PPW; ++p)
        #pragma unroll
        for (int r = 0; r < 16; ++r) best[p][r] = 1e30f;

    // staging: each thread ferries 4 frags/chunk (64 B) via registers
    bf16x8 rg[4];
    const int soff = w * 256 + lane;
    #define GLOAD(c) { const bf16x8* g = bp + (size_t)(c) * (CH*64) + soff; \
        _Pragma("unroll") for (int i = 0; i < 4; ++i) rg[i] = g[i * 64]; }
    #define SWRITE(pb) { bf16x8* s = &sbuf[pb][soff]; \
        _Pragma("unroll") for (int i = 0; i < 4; ++i) s[i * 64] = rg[i]; }

    GLOAD(0); SWRITE(0); GLOAD(1);
    __syncthreads();

    for (int c = 0; c < NC; ++c) {
        const int pb = c & 1;
        if (c + 1 < NC) SWRITE(pb ^ 1);
        if (c + 2 < NC) GLOAD(c + 2);
        #pragma unroll 8
        for (int j = 0; j < CH; ++j) {
            const bf16x8 bc = sbuf[pb][j * 64 + lane];
            #pragma unroll
            for (int p = 0; p < PPW; ++p) {
                f32x16 d = __builtin_amdgcn_mfma_f32_32x32x16_bf16(afrag[p], bc, czero, 0, 0, 0);
                #pragma unroll
                for (int r = 0; r < 16; ++r) best[p][r] = fminf(best[p][r], d[r]);
            }
        }
        __syncthreads();
    }

    // Row-mins: min across the 32 lanes of each half (32 m-residues), then sum.
    float bsum = 0.f;
    #pragma unroll
    for (int p = 0; p < PPW; ++p) {
        float s = 0.f;
        #pragma unroll
        for (int r = 0; r < 16; ++r) {
            float v = best[p][r];
            v = fminf(v, __shfl_xor(v, 1,  64));
            v = fminf(v, __shfl_xor(v, 2,  64));
            v = fminf(v, __shfl_xor(v, 4,  64));
            v = fminf(v, __shfl_xor(v, 8,  64));
            v = fminf(v, __shfl_xor(v, 16, 64));
            s += v;                       // 16 final row-mins of this half
        }
        bsum += s + __shfl_xor(s, 32, 64);  // add other half's 16 rows
    }
    // one value per wave -> LDS -> one atomicAdd per block
    if (lane == 0) wsum[w] = bsum;
    __syncthreads();
    if (threadIdx.x == 0) {
        const float scale = 100.0f * 0.5f / ((float)B_DIM * (float)N_DIM);
        atomicAdd(out, (wsum[0] + wsum[1] + wsum[2] + wsum[3]) * scale);
    }
}

extern "C" void kernel_launch(void* const* d_in, const int* in_sizes, int n_in,
                              void* d_out, int out_size, void* d_ws, size_t ws_size,
                              hipStream_t stream) {
    const float* pred = (const float*)d_in[0];
    const float* gt   = (const float*)d_in[1];
    float* out = (float*)d_out;
    unsigned short* bpack = (unsigned short*)d_ws;   // 4 MiB

    chamfer_prep<<<(2 * B_DIM * N_DIM) / 256, 256, 0, stream>>>(pred, gt, bpack, out);

    // dirb x n-chunks(256 pts) = 16 x 32 = 512 blocks, 2/CU
    dim3 grid(16, N_DIM / (32 * 4 * PPW));
    chamfer_partial<<<grid, BLOCK, 0, stream>>>(pred, gt, (const bf16x8*)bpack, out);
}